// Round 6
// baseline (154.736 us; speedup 1.0000x reference)
//
#include <hip/hip_runtime.h>
#include <hip/hip_cooperative_groups.h>
#include <math.h>

namespace cg = cooperative_groups;

#define NROWS 2048
#define MCOLS 32

// Taylor erf on |x| <= 1/(2*sqrt(2)): erf(x) = c1 x + c3 x^3 + c5 x^5 + c7 x^7
#define C1 1.1283791671f
#define C3 (-0.3761263890f)
#define C5 0.1128379167f
#define C7 (-0.0268661706f)

// Single cooperative kernel: 256 blocks x 256 threads, thread owns element
// i = b*256 + tid (= row-major (a,k), k = tid&31 since 256 % 32 == 0).
//
// Phase 1: block-local moment partials M'_q[k] = sum_rows e*t^q (q=0..7) and
//          column max -> per-block ws slots (no atomics, no init pass).
// grid.sync()
// Phase 2: every block reduces all 256 partial sets (L2-resident), 32 threads
//          build per-column Horner coeffs D_0..7, scale s, 0.5*sum(e) in LDS.
// Phase 3: cumsum_j = 0.5*S + 0.5*(sum_i (-t_j s)^i D_i + e_j);
//          loss contrib (log(cum)-risk)*event; block reduce; 1 atomicAdd/block.
__global__ __launch_bounds__(256) void k_fused(const float* __restrict__ expr,
                                               const float* __restrict__ tr,
                                               const float* __restrict__ risk,
                                               const float* __restrict__ event,
                                               const float* __restrict__ sigma,
                                               float* __restrict__ partial,
                                               float* __restrict__ pmax,
                                               float* __restrict__ out) {
    cg::grid_group grid = cg::this_grid();
    const int tid = threadIdx.x;
    const int b   = blockIdx.x;
    const int i   = b * 256 + tid;
    const int k   = tid & 31;
    const int q   = tid >> 5;

    __shared__ float sm_t[256];
    __shared__ float sm_e[256];
    __shared__ float sD[256];
    __shared__ float sSc[32];
    __shared__ float sSh[32];
    __shared__ float warpsum[4];

    // ---- Phase 1 ----
    float rv = risk[i];
    float t  = __expf(expr[i] - tr[i]);
    float e  = __expf(rv);
    sm_t[tid] = t;
    sm_e[tid] = e;
    __syncthreads();

    float part = 0.0f, mx = 0.0f;
#pragma unroll
    for (int r = 0; r < 8; r++) {
        float tt = sm_t[r * 32 + k];   // lanes l and l+32 read same addr: broadcast
        float ee = sm_e[r * 32 + k];
        float p = ee;
#pragma unroll 7
        for (int m = 0; m < q; m++) p *= tt;   // e * t^q
        part += p;
        mx = fmaxf(mx, tt);
    }
    partial[b * 256 + tid] = part;
    if (q == 0) pmax[b * 32 + k] = mx;
    if (i == 0) out[0] = 0.0f;

    __threadfence();
    grid.sync();

    // ---- Phase 2: redundant per-block reduction (L2-resident) ----
    float a0 = 0.f, a1 = 0.f, a2 = 0.f, a3 = 0.f;
    for (int bb = 0; bb < 256; bb += 4) {
        a0 += partial[(bb + 0) * 256 + tid];
        a1 += partial[(bb + 1) * 256 + tid];
        a2 += partial[(bb + 2) * 256 + tid];
        a3 += partial[(bb + 3) * 256 + tid];
    }
    float Msum = (a0 + a1) + (a2 + a3);

    float mxc = 0.0f;
    if (tid < 32) {
        for (int bb = 0; bb < 256; bb++)
            mxc = fmaxf(mxc, pmax[bb * 32 + tid]);
    }
    __syncthreads();               // sm_t reuse below
    sm_t[tid] = Msum;              // moment store: sm_t[q*32 + k]
    __syncthreads();

    if (tid < 32) {
        float s = 1.0f / (mxc * 2.0f * sigma[0] * sqrtf(2.0f));
        float M[8];
        float sp = 1.0f;
#pragma unroll
        for (int qq = 0; qq < 8; qq++) { M[qq] = sm_t[qq * 32 + tid] * sp; sp *= s; }
        sD[0 * 32 + tid] = C1 * M[1] +         C3 * M[3] +         C5 * M[5] +        C7 * M[7];
        sD[1 * 32 + tid] = C1 * M[0] + 3.0f *  C3 * M[2] + 5.0f *  C5 * M[4] + 7.0f * C7 * M[6];
        sD[2 * 32 + tid] = 3.0f * C3 * M[1] + 10.0f * C5 * M[3] + 21.0f * C7 * M[5];
        sD[3 * 32 + tid] = C3 * M[0] + 10.0f * C5 * M[2] + 35.0f * C7 * M[4];
        sD[4 * 32 + tid] = 5.0f * C5 * M[1] + 35.0f * C7 * M[3];
        sD[5 * 32 + tid] = C5 * M[0] + 21.0f * C7 * M[2];
        sD[6 * 32 + tid] = 7.0f * C7 * M[1];
        sD[7 * 32 + tid] = C7 * M[0];
        sSc[tid] = s;
        sSh[tid] = 0.5f * M[0];
    }
    __syncthreads();

    // ---- Phase 3 ----
    float w = -(t * sSc[k]);
    float h = sD[7 * 32 + k];
#pragma unroll
    for (int qq = 6; qq >= 0; qq--) h = fmaf(h, w, sD[qq * 32 + k]);
    float cum = sSh[k] + 0.5f * (h + e);
    float c = (__logf(cum) - rv) * event[i];

    for (int off = 32; off > 0; off >>= 1)
        c += __shfl_down(c, off, 64);
    if ((tid & 63) == 0) warpsum[tid >> 6] = c;
    __syncthreads();
    if (tid == 0) {
        float s = (warpsum[0] + warpsum[1]) + (warpsum[2] + warpsum[3]);
        atomicAdd(out, s);
    }
}

extern "C" void kernel_launch(void* const* d_in, const int* in_sizes, int n_in,
                              void* d_out, int out_size, void* d_ws, size_t ws_size,
                              hipStream_t stream) {
    const float* risk  = (const float*)d_in[0];
    const float* expr  = (const float*)d_in[1];
    const float* tr    = (const float*)d_in[2];
    const float* event = (const float*)d_in[3];
    const float* sigma = (const float*)d_in[4];
    float* out = (float*)d_out;

    float* ws_partial = (float*)d_ws;              // 256 * 256 floats
    float* ws_pmax    = ws_partial + 256 * 256;    // 256 * 32 floats

    void* args[] = { (void*)&expr, (void*)&tr, (void*)&risk, (void*)&event,
                     (void*)&sigma, (void*)&ws_partial, (void*)&ws_pmax,
                     (void*)&out };
    hipLaunchCooperativeKernel((const void*)k_fused, dim3(256), dim3(256),
                               args, 0, stream);
}

// Round 7
// 77.671 us; speedup vs baseline: 1.9922x; 1.9922x over previous
//
#include <hip/hip_runtime.h>
#include <math.h>

#define NROWS 2048
#define MCOLS 32

// Taylor erf on |x| <= 1/(2*sqrt(2)): erf(x) = c1 x + c3 x^3 + c5 x^5 + c7 x^7
#define C1 1.1283791671f
#define C3 (-0.3761263890f)
#define C5 0.1128379167f
#define C7 (-0.0268661706f)

// K1: 64 blocks x 1024 threads; element i = b*1024+tid (row-major (a,k), k=i&31).
// Stage t=exp(expr-tr), e=exp(risk) in LDS; threads tid<256 = (q,k) reduce the
// block's 32 rows into moment partials M'_q[k] = sum e*t^q -> partial[b*256+tid];
// q==0 threads also write the block's column max. No atomics, no init dispatch.
__global__ __launch_bounds__(1024) void k_moments(const float* __restrict__ expr,
                                                  const float* __restrict__ tr,
                                                  const float* __restrict__ risk,
                                                  float* __restrict__ partial,
                                                  float* __restrict__ pmax,
                                                  float* __restrict__ out) {
    int tid = threadIdx.x, b = blockIdx.x;
    int i = b * 1024 + tid;

    __shared__ float sm_t[1024];
    __shared__ float sm_e[1024];
    sm_t[tid] = __expf(expr[i] - tr[i]);
    sm_e[tid] = __expf(risk[i]);
    __syncthreads();

    if (tid < 256) {
        int q = tid >> 5;               // 0..7
        int k = tid & 31;
        float part = 0.0f, mx = 0.0f;
#pragma unroll
        for (int r = 0; r < 32; r++) {
            float tt = sm_t[r * 32 + k];   // lanes l, l+32: same addr -> broadcast
            float ee = sm_e[r * 32 + k];
            float p = ee;
#pragma unroll 7
            for (int m = 0; m < q; m++) p *= tt;   // e * t^q
            part += p;
            mx = fmaxf(mx, tt);
        }
        partial[b * 256 + tid] = part;
        if (q == 0) pmax[b * 32 + k] = mx;
    }
    if (i == 0) out[0] = 0.0f;
}

// K2: 256 blocks x 256 threads. Prologue: every block reduces the 64 partial
// moment sets + column maxes (L2-resident; 16 MB aggregate), 32 threads build
// per-column Horner coeffs D_0..7 / scale / 0.5*sum(e) in LDS. Main: recompute
// t,e from inputs, Horner + log, shuffle reduce, one atomicAdd per block.
__global__ __launch_bounds__(256) void k_loss(const float* __restrict__ expr,
                                              const float* __restrict__ tr,
                                              const float* __restrict__ risk,
                                              const float* __restrict__ event,
                                              const float* __restrict__ sigma,
                                              const float* __restrict__ partial,
                                              const float* __restrict__ pmax,
                                              float* __restrict__ out) {
    int tid = threadIdx.x;
    __shared__ float sM[256];
    __shared__ float sD[256];
    __shared__ float sSc[32];
    __shared__ float sSh[32];
    __shared__ float warpsum[4];

    float a0 = 0.f, a1 = 0.f, a2 = 0.f, a3 = 0.f;
#pragma unroll
    for (int bb = 0; bb < 64; bb += 4) {
        a0 += partial[(bb + 0) * 256 + tid];
        a1 += partial[(bb + 1) * 256 + tid];
        a2 += partial[(bb + 2) * 256 + tid];
        a3 += partial[(bb + 3) * 256 + tid];
    }
    sM[tid] = (a0 + a1) + (a2 + a3);

    float mxc = 0.0f;
    if (tid < 32) {
#pragma unroll
        for (int bb = 0; bb < 64; bb++)
            mxc = fmaxf(mxc, pmax[bb * 32 + tid]);
    }
    __syncthreads();

    if (tid < 32) {
        int k = tid;
        float s = 1.0f / (mxc * 2.0f * sigma[0] * sqrtf(2.0f));
        float M[8];
        float sp = 1.0f;
#pragma unroll
        for (int q = 0; q < 8; q++) { M[q] = sM[q * 32 + k] * sp; sp *= s; }
        sD[0 * 32 + k] = C1 * M[1] +         C3 * M[3] +         C5 * M[5] +        C7 * M[7];
        sD[1 * 32 + k] = C1 * M[0] + 3.0f *  C3 * M[2] + 5.0f *  C5 * M[4] + 7.0f * C7 * M[6];
        sD[2 * 32 + k] = 3.0f * C3 * M[1] + 10.0f * C5 * M[3] + 21.0f * C7 * M[5];
        sD[3 * 32 + k] = C3 * M[0] + 10.0f * C5 * M[2] + 35.0f * C7 * M[4];
        sD[4 * 32 + k] = 5.0f * C5 * M[1] + 35.0f * C7 * M[3];
        sD[5 * 32 + k] = C5 * M[0] + 21.0f * C7 * M[2];
        sD[6 * 32 + k] = 7.0f * C7 * M[1];
        sD[7 * 32 + k] = C7 * M[0];
        sSc[k] = s;
        sSh[k] = 0.5f * M[0];
    }
    __syncthreads();

    int i = blockIdx.x * 256 + tid;     // row-major (j,k), k = tid&31
    int k = tid & 31;
    float rv = risk[i];
    float t  = __expf(expr[i] - tr[i]);
    float e  = __expf(rv);
    float w = -(t * sSc[k]);
    float h = sD[7 * 32 + k];
#pragma unroll
    for (int q = 6; q >= 0; q--) h = fmaf(h, w, sD[q * 32 + k]);
    float cum = sSh[k] + 0.5f * (h + e);
    float c = (__logf(cum) - rv) * event[i];

    for (int off = 32; off > 0; off >>= 1)
        c += __shfl_down(c, off, 64);
    if ((tid & 63) == 0) warpsum[tid >> 6] = c;
    __syncthreads();
    if (tid == 0) {
        float s = (warpsum[0] + warpsum[1]) + (warpsum[2] + warpsum[3]);
        atomicAdd(out, s);
    }
}

extern "C" void kernel_launch(void* const* d_in, const int* in_sizes, int n_in,
                              void* d_out, int out_size, void* d_ws, size_t ws_size,
                              hipStream_t stream) {
    const float* risk  = (const float*)d_in[0];
    const float* expr  = (const float*)d_in[1];
    const float* tr    = (const float*)d_in[2];
    const float* event = (const float*)d_in[3];
    const float* sigma = (const float*)d_in[4];
    float* out = (float*)d_out;

    float* ws_partial = (float*)d_ws;            // 64 * 256 floats
    float* ws_pmax    = ws_partial + 64 * 256;   // 64 * 32 floats

    k_moments<<<64, 1024, 0, stream>>>(expr, tr, risk, ws_partial, ws_pmax, out);
    k_loss<<<256, 256, 0, stream>>>(expr, tr, risk, event, sigma,
                                    ws_partial, ws_pmax, out);
}